// Round 14
// baseline (21.555 us; speedup 1.0000x reference)
//
#include <hip/hip_runtime.h>
#include <math.h>

#define DIM 16

typedef float v2f __attribute__((ext_vector_type(2)));
static __device__ __forceinline__ v2f vsplat(float v) { return (v2f){v, v}; }
static __device__ __forceinline__ v2f vfma(v2f a, v2f b, v2f c) {
  return __builtin_elementwise_fma(a, b, c);     // -> v_pk_fma_f32
}

// ---------------------------------------------------------------------------
// Precompute kernel (unchanged, proven): build C[4][81] into d_ws.
// ---------------------------------------------------------------------------
__global__ __launch_bounds__(256) void quanv_precompute(const float* __restrict__ w,
                                                        float* __restrict__ C) {
  __shared__ float Ur[DIM][20];
  __shared__ float Ui[DIM][20];
  __shared__ float Ad[4][DIM][DIM];
  const int tid = threadIdx.x;

  if (tid < DIM) {
    float ur[DIM], ui[DIM];
#pragma unroll
    for (int m = 0; m < DIM; ++m) { ur[m] = (m == tid) ? 1.0f : 0.0f; ui[m] = 0.0f; }
#pragma unroll
    for (int l = 0; l < 2; ++l) {
#pragma unroll
      for (int q = 0; q < 4; ++q) {
        const float phi = w[l * 12 + q * 3 + 0];
        const float th  = w[l * 12 + q * 3 + 1];
        const float om  = w[l * 12 + q * 3 + 2];
        const float a  = 0.5f * (phi + om);
        const float bb = 0.5f * (phi - om);
        float ct, st, ca, sa, cb, sb;
        __sincosf(0.5f * th, &st, &ct);
        __sincosf(a, &sa, &ca);
        __sincosf(bb, &sb, &cb);
        const float g00r =  ca * ct, g00i = -sa * ct;
        const float g01r = -cb * st, g01i = -sb * st;
        const float g10r =  cb * st, g10i = -sb * st;
        const float g11r =  ca * ct, g11i =  sa * ct;
        const int bit = 1 << (3 - q);
#pragma unroll
        for (int m = 0; m < DIM; ++m) {
          if (m & bit) continue;
          const int m1 = m | bit;
          const float v0r = ur[m],  v0i = ui[m];
          const float v1r = ur[m1], v1i = ui[m1];
          ur[m]  = g00r * v0r - g00i * v0i + g01r * v1r - g01i * v1i;
          ui[m]  = g00r * v0i + g00i * v0r + g01r * v1i + g01i * v1r;
          ur[m1] = g10r * v0r - g10i * v0i + g11r * v1r - g11i * v1i;
          ui[m1] = g10r * v0i + g10i * v0r + g11r * v1i + g11i * v1r;
        }
      }
      const int r = (l % 3) + 1;
#pragma unroll
      for (int q = 0; q < 4; ++q) {
        const int cbit = 1 << (3 - q);
        const int tbit = 1 << (3 - ((q + r) & 3));
#pragma unroll
        for (int m = 0; m < DIM; ++m) {
          if ((m & cbit) && !(m & tbit)) {
            const int m1 = m | tbit;
            float t;
            t = ur[m]; ur[m] = ur[m1]; ur[m1] = t;
            t = ui[m]; ui[m] = ui[m1]; ui[m1] = t;
          }
        }
      }
    }
#pragma unroll
    for (int m = 0; m < DIM; ++m) { Ur[tid][m] = ur[m]; Ui[tid][m] = ui[m]; }
  }
  __syncthreads();

  {
    const int j = tid >> 4, k = tid & 15;
    float term[DIM];
#pragma unroll
    for (int m = 0; m < DIM; ++m)
      term[m] = Ur[j][m] * Ur[k][m] + Ui[j][m] * Ui[k][m];
#pragma unroll
    for (int i = 0; i < 4; ++i) {
      float s = 0.0f;
#pragma unroll
      for (int m = 0; m < DIM; ++m)
        s += ((m >> (3 - i)) & 1) ? -term[m] : term[m];
      Ad[i][j][k] = s;
    }
  }
  __syncthreads();

  for (int idx = tid; idx < 4 * 81; idx += 256) {
    const int i = idx / 81;
    const int rr = idx - i * 81;
    const int v0 = rr / 27, v1 = (rr / 9) % 3, v2 = (rr / 3) % 3, v3 = rr % 3;
    float s = 0.0f;
#pragma unroll
    for (int b = 0; b < 16; ++b) {
      const int b0 = (b >> 3) & 1, b1 = (b >> 2) & 1, b2 = (b >> 1) & 1, b3 = b & 1;
      const int k0 = (v0 == 2) ? (b0 ^ 1) : b0;
      const int k1 = (v1 == 2) ? (b1 ^ 1) : b1;
      const int k2 = (v2 == 2) ? (b2 ^ 1) : b2;
      const int k3 = (v3 == 2) ? (b3 ^ 1) : b3;
      const int neg = (((v0 == 1) & b0) ^ ((v1 == 1) & b1) ^
                       ((v2 == 1) & b2) ^ ((v3 == 1) & b3));
      const int k = (k0 << 3) | (k1 << 2) | (k2 << 1) | k3;
      const float term = Ad[i][b][k];
      s += neg ? -term : term;
    }
    C[idx] = 0.0625f * s;
  }
}

// ---------------------------------------------------------------------------
// Main kernel: FOUR horizontally-adjacent patches per thread as two pk-pairs.
//   - raw-HW trig: e^{2x}=v_exp(x*2log2e) via exp2; tanh=fma(-2,rcp(u+1),1);
//     sin(pi/2*t)=v_sin(t*0.25) (v_sin/v_cos take REVOLUTIONS; |arg|<=0.25,
//     no range reduction needed).
//   - d0/d1/d2 scalar loads + splats shared by both pk-pairs.
//   - one float4 store per output plane.
// ---------------------------------------------------------------------------
static __device__ __forceinline__ void pix_trig(float xx, float& c, float& s) {
  xx = fminf(10.0f, fmaxf(-10.0f, xx));                       // v_med3
  const float u = __builtin_amdgcn_exp2f(xx * 2.885390081777927f); // e^{2x}
  const float t = fmaf(-2.0f, __builtin_amdgcn_rcpf(u + 1.0f), 1.0f); // tanh
  const float r = t * 0.25f;                                  // revolutions
  s = __builtin_amdgcn_sinf(r);
  c = __builtin_amdgcn_cosf(r);
}

__global__ __launch_bounds__(256) void quanv_main(const float* __restrict__ x,
                                                  const float* __restrict__ C,
                                                  float* __restrict__ out) {
  const int Q  = blockIdx.x * 256 + threadIdx.x;   // 200704 quads (784 blocks)
  const int b  = Q / 3136;                         // 112*28 quads per image
  const int rm = Q - b * 3136;
  const int i  = rm / 28;
  const int jq = rm - i * 28;                      // quad col: patches 4jq..4jq+3

  const float* px = x + (size_t)b * 50176 + (size_t)(2 * i) * 224 + 8 * jq;
  const float4 r0a = *(const float4*)(px);         // patches 0,1 row0
  const float4 r0b = *(const float4*)(px + 4);     // patches 2,3 row0
  const float4 r1a = *(const float4*)(px + 224);
  const float4 r1b = *(const float4*)(px + 228);

  // pair A = patches (0,1), pair B = patches (2,3)
  float c0a0, s0a0, c1a0, s1a0, c2a0, s2a0, c3a0, s3a0;   // patch0
  float c0a1, s0a1, c1a1, s1a1, c2a1, s2a1, c3a1, s3a1;   // patch1
  float c0b0, s0b0, c1b0, s1b0, c2b0, s2b0, c3b0, s3b0;   // patch2
  float c0b1, s0b1, c1b1, s1b1, c2b1, s2b1, c3b1, s3b1;   // patch3
  pix_trig(r0a.x, c0a0, s0a0);  pix_trig(r0a.y, c1a0, s1a0);
  pix_trig(r1a.x, c2a0, s2a0);  pix_trig(r1a.y, c3a0, s3a0);
  pix_trig(r0a.z, c0a1, s0a1);  pix_trig(r0a.w, c1a1, s1a1);
  pix_trig(r1a.z, c2a1, s2a1);  pix_trig(r1a.w, c3a1, s3a1);
  pix_trig(r0b.x, c0b0, s0b0);  pix_trig(r0b.y, c1b0, s1b0);
  pix_trig(r1b.x, c2b0, s2b0);  pix_trig(r1b.y, c3b0, s3b0);
  pix_trig(r0b.z, c0b1, s0b1);  pix_trig(r0b.w, c1b1, s1b1);
  pix_trig(r1b.z, c2b1, s2b1);  pix_trig(r1b.w, c3b1, s3b1);

  const v2f g0A[3] = {vsplat(1.0f), (v2f){c0a0, c0a1}, (v2f){s0a0, s0a1}};
  const v2f g1A[3] = {vsplat(1.0f), (v2f){c1a0, c1a1}, (v2f){s1a0, s1a1}};
  const v2f g2A[3] = {vsplat(1.0f), (v2f){c2a0, c2a1}, (v2f){s2a0, s2a1}};
  const v2f c3A = (v2f){c3a0, c3a1}, s3A = (v2f){s3a0, s3a1};
  const v2f g0B[3] = {vsplat(1.0f), (v2f){c0b0, c0b1}, (v2f){s0b0, s0b1}};
  const v2f g1B[3] = {vsplat(1.0f), (v2f){c1b0, c1b1}, (v2f){s1b0, s1b1}};
  const v2f g2B[3] = {vsplat(1.0f), (v2f){c2b0, c2b1}, (v2f){s2b0, s2b1}};
  const v2f c3B = (v2f){c3b0, c3b1}, s3B = (v2f){s3b0, s3b1};

  const int obase = b * 50176 + i * 112 + 4 * jq;  // out b-stride 4*12544

#pragma unroll
  for (int oi = 0; oi < 4; ++oi) {
    const float* D = C + oi * 81;
    v2f a0A, a1A, a2A, a0B, a1B, a2B;
#pragma unroll
    for (int v0 = 0; v0 < 3; ++v0) {
#pragma unroll
      for (int v1 = 0; v1 < 3; ++v1) {
#pragma unroll
        for (int v2 = 0; v2 < 3; ++v2) {
          const int base = ((v0 * 3 + v1) * 3 + v2) * 3;
          const float d0 = D[base], d1 = D[base + 1], d2 = D[base + 2];
          const v2f vd0 = vsplat(d0), vd1 = vsplat(d1), vd2 = vsplat(d2);
          const v2f tA = vfma(s3A, vd2, vfma(c3A, vd1, vd0));
          const v2f tB = vfma(s3B, vd2, vfma(c3B, vd1, vd0));
          a2A = (v2 == 0) ? tA : vfma(g2A[v2], tA, a2A);
          a2B = (v2 == 0) ? tB : vfma(g2B[v2], tB, a2B);
        }
        a1A = (v1 == 0) ? a2A : vfma(g1A[v1], a2A, a1A);
        a1B = (v1 == 0) ? a2B : vfma(g1B[v1], a2B, a1B);
      }
      a0A = (v0 == 0) ? a1A : vfma(g0A[v0], a1A, a0A);
      a0B = (v0 == 0) ? a1B : vfma(g0B[v0], a1B, a0B);
    }
    *(float4*)(&out[obase + oi * 12544]) = (float4){a0A.x, a0A.y, a0B.x, a0B.y};
  }
}

extern "C" void kernel_launch(void* const* d_in, const int* in_sizes, int n_in,
                              void* d_out, int out_size, void* d_ws, size_t ws_size,
                              hipStream_t stream) {
  const float* x = (const float*)d_in[0];   // (64,1,224,224) f32
  const float* w = (const float*)d_in[1];   // (2,4,3) f32
  float* out = (float*)d_out;               // (64,4,112,112) f32
  float* C   = (float*)d_ws;                // 4*81 floats

  quanv_precompute<<<1, 256, 0, stream>>>(w, C);
  quanv_main<<<784, 256, 0, stream>>>(x, C, out);
}

// Round 15
// 20.607 us; speedup vs baseline: 1.0460x; 1.0460x over previous
//
#include <hip/hip_runtime.h>
#include <math.h>

#define DIM 16

typedef float v2f __attribute__((ext_vector_type(2)));
static __device__ __forceinline__ v2f vsplat(float v) { return (v2f){v, v}; }
static __device__ __forceinline__ v2f vfma(v2f a, v2f b, v2f c) {
  return __builtin_elementwise_fma(a, b, c);     // -> v_pk_fma_f32
}

// ---------------------------------------------------------------------------
// Precompute kernel (unchanged, proven): build C[4][81] into d_ws.
// ---------------------------------------------------------------------------
__global__ __launch_bounds__(256) void quanv_precompute(const float* __restrict__ w,
                                                        float* __restrict__ C) {
  __shared__ float Ur[DIM][20];
  __shared__ float Ui[DIM][20];
  __shared__ float Ad[4][DIM][DIM];
  const int tid = threadIdx.x;

  if (tid < DIM) {
    float ur[DIM], ui[DIM];
#pragma unroll
    for (int m = 0; m < DIM; ++m) { ur[m] = (m == tid) ? 1.0f : 0.0f; ui[m] = 0.0f; }
#pragma unroll
    for (int l = 0; l < 2; ++l) {
#pragma unroll
      for (int q = 0; q < 4; ++q) {
        const float phi = w[l * 12 + q * 3 + 0];
        const float th  = w[l * 12 + q * 3 + 1];
        const float om  = w[l * 12 + q * 3 + 2];
        const float a  = 0.5f * (phi + om);
        const float bb = 0.5f * (phi - om);
        float ct, st, ca, sa, cb, sb;
        __sincosf(0.5f * th, &st, &ct);
        __sincosf(a, &sa, &ca);
        __sincosf(bb, &sb, &cb);
        const float g00r =  ca * ct, g00i = -sa * ct;
        const float g01r = -cb * st, g01i = -sb * st;
        const float g10r =  cb * st, g10i = -sb * st;
        const float g11r =  ca * ct, g11i =  sa * ct;
        const int bit = 1 << (3 - q);
#pragma unroll
        for (int m = 0; m < DIM; ++m) {
          if (m & bit) continue;
          const int m1 = m | bit;
          const float v0r = ur[m],  v0i = ui[m];
          const float v1r = ur[m1], v1i = ui[m1];
          ur[m]  = g00r * v0r - g00i * v0i + g01r * v1r - g01i * v1i;
          ui[m]  = g00r * v0i + g00i * v0r + g01r * v1i + g01i * v1r;
          ur[m1] = g10r * v0r - g10i * v0i + g11r * v1r - g11i * v1i;
          ui[m1] = g10r * v0i + g10i * v0r + g11r * v1i + g11i * v1r;
        }
      }
      const int r = (l % 3) + 1;
#pragma unroll
      for (int q = 0; q < 4; ++q) {
        const int cbit = 1 << (3 - q);
        const int tbit = 1 << (3 - ((q + r) & 3));
#pragma unroll
        for (int m = 0; m < DIM; ++m) {
          if ((m & cbit) && !(m & tbit)) {
            const int m1 = m | tbit;
            float t;
            t = ur[m]; ur[m] = ur[m1]; ur[m1] = t;
            t = ui[m]; ui[m] = ui[m1]; ui[m1] = t;
          }
        }
      }
    }
#pragma unroll
    for (int m = 0; m < DIM; ++m) { Ur[tid][m] = ur[m]; Ui[tid][m] = ui[m]; }
  }
  __syncthreads();

  {
    const int j = tid >> 4, k = tid & 15;
    float term[DIM];
#pragma unroll
    for (int m = 0; m < DIM; ++m)
      term[m] = Ur[j][m] * Ur[k][m] + Ui[j][m] * Ui[k][m];
#pragma unroll
    for (int i = 0; i < 4; ++i) {
      float s = 0.0f;
#pragma unroll
      for (int m = 0; m < DIM; ++m)
        s += ((m >> (3 - i)) & 1) ? -term[m] : term[m];
      Ad[i][j][k] = s;
    }
  }
  __syncthreads();

  for (int idx = tid; idx < 4 * 81; idx += 256) {
    const int i = idx / 81;
    const int rr = idx - i * 81;
    const int v0 = rr / 27, v1 = (rr / 9) % 3, v2 = (rr / 3) % 3, v3 = rr % 3;
    float s = 0.0f;
#pragma unroll
    for (int b = 0; b < 16; ++b) {
      const int b0 = (b >> 3) & 1, b1 = (b >> 2) & 1, b2 = (b >> 1) & 1, b3 = b & 1;
      const int k0 = (v0 == 2) ? (b0 ^ 1) : b0;
      const int k1 = (v1 == 2) ? (b1 ^ 1) : b1;
      const int k2 = (v2 == 2) ? (b2 ^ 1) : b2;
      const int k3 = (v3 == 2) ? (b3 ^ 1) : b3;
      const int neg = (((v0 == 1) & b0) ^ ((v1 == 1) & b1) ^
                       ((v2 == 1) & b2) ^ ((v3 == 1) & b3));
      const int k = (k0 << 3) | (k1 << 2) | (k2 << 1) | k3;
      const float term = Ad[i][b][k];
      s += neg ? -term : term;
    }
    C[idx] = 0.0625f * s;
  }
}

// ---------------------------------------------------------------------------
// Main kernel: R12's proven 2-patch pk-FMA skeleton + raw HW trig.
//   e^{2x} = exp2(x*2log2e); tanh = fma(-2, rcp(u+1), 1)  (saturates cleanly
//   at +-1 for |x| large, no clamp needed); sin(pi/2 * t) = v_sin(t*0.25)
//   (HW sin/cos take revolutions, |arg|<=0.25 -> no range reduction).
// ---------------------------------------------------------------------------
static __device__ __forceinline__ void pix_trig(float xx, float& c, float& s) {
  const float u = __builtin_amdgcn_exp2f(xx * 2.885390081777927f); // e^{2x}
  const float t = fmaf(-2.0f, __builtin_amdgcn_rcpf(u + 1.0f), 1.0f); // tanh
  const float r = t * 0.25f;                                  // revolutions
  s = __builtin_amdgcn_sinf(r);
  c = __builtin_amdgcn_cosf(r);
}

__global__ __launch_bounds__(256) void quanv_main(const float* __restrict__ x,
                                                  const float* __restrict__ C,
                                                  float* __restrict__ out) {
  const int P  = blockIdx.x * 256 + threadIdx.x;   // 401408 pair-ids (1568 blocks)
  const int b  = P / 6272;                         // 112*56 pairs per image
  const int rm = P - b * 6272;
  const int i  = rm / 56;
  const int jp = rm - i * 56;                      // pair col; patches j=2jp, 2jp+1

  const float* px = x + (size_t)b * 50176 + (size_t)(2 * i) * 224 + 4 * jp;
  const float4 r0 = *(const float4*)(px);          // patch0: .x.y  patch1: .z.w
  const float4 r1 = *(const float4*)(px + 224);

  float c0a, s0a, c1a, s1a, c2a, s2a, c3a, s3a;    // patch0 (left)
  float c0b, s0b, c1b, s1b, c2b, s2b, c3b, s3b;    // patch1 (right)
  pix_trig(r0.x, c0a, s0a);
  pix_trig(r0.y, c1a, s1a);
  pix_trig(r1.x, c2a, s2a);
  pix_trig(r1.y, c3a, s3a);
  pix_trig(r0.z, c0b, s0b);
  pix_trig(r0.w, c1b, s1b);
  pix_trig(r1.z, c2b, s2b);
  pix_trig(r1.w, c3b, s3b);

  const v2f g0v[3] = {vsplat(1.0f), (v2f){c0a, c0b}, (v2f){s0a, s0b}};
  const v2f g1v[3] = {vsplat(1.0f), (v2f){c1a, c1b}, (v2f){s1a, s1b}};
  const v2f g2v[3] = {vsplat(1.0f), (v2f){c2a, c2b}, (v2f){s2a, s2b}};
  const v2f c3v = (v2f){c3a, c3b};
  const v2f s3v = (v2f){s3a, s3b};

  const int obase = b * 50176 + i * 112 + 2 * jp;  // out b-stride 4*12544

#pragma unroll
  for (int oi = 0; oi < 4; ++oi) {
    const float* D = C + oi * 81;
    v2f a0, a1, a2;
#pragma unroll
    for (int v0 = 0; v0 < 3; ++v0) {
#pragma unroll
      for (int v1 = 0; v1 < 3; ++v1) {
#pragma unroll
        for (int v2 = 0; v2 < 3; ++v2) {
          const int base = ((v0 * 3 + v1) * 3 + v2) * 3;
          const float d0 = D[base], d1 = D[base + 1], d2 = D[base + 2];
          const v2f t = vfma(s3v, vsplat(d2), vfma(c3v, vsplat(d1), vsplat(d0)));
          a2 = (v2 == 0) ? t : vfma(g2v[v2], t, a2);
        }
        a1 = (v1 == 0) ? a2 : vfma(g1v[v1], a2, a1);
      }
      a0 = (v0 == 0) ? a1 : vfma(g0v[v0], a1, a0);
    }
    *(float2*)(&out[obase + oi * 12544]) = (float2){a0.x, a0.y};
  }
}

extern "C" void kernel_launch(void* const* d_in, const int* in_sizes, int n_in,
                              void* d_out, int out_size, void* d_ws, size_t ws_size,
                              hipStream_t stream) {
  const float* x = (const float*)d_in[0];   // (64,1,224,224) f32
  const float* w = (const float*)d_in[1];   // (2,4,3) f32
  float* out = (float*)d_out;               // (64,4,112,112) f32
  float* C   = (float*)d_ws;                // 4*81 floats

  quanv_precompute<<<1, 256, 0, stream>>>(w, C);
  quanv_main<<<1568, 256, 0, stream>>>(x, C, out);
}